// Round 8
// baseline (306.629 us; speedup 1.0000x reference)
//
#include <hip/hip_runtime.h>
#include <hip/hip_bf16.h>
#include <math.h>

// Mixer2dTriU: B=64, T=512, C=512, fp32 in/out.
// Pipeline (5 launches):
//   memset(red); prep (conv_weights + ln_stats); ln1_norm_t;
//   gemm_mixer (128^2 tiles, fused ln2 stats);
//   gemm_mlp   (FUSED ln2_norm + d1 + d2, barrier-free K-loops).
//
// gemm_mlp (new): per block, one 32-row strip of one batch.
//   stage: A1 = ln2(Z[strip]) -> 32 KB swizzled LDS (X2 never materialized)
//   GEMM1: H = gelu(A1 @ W1^T + b1): A from LDS, B fragments DIRECT FROM
//          GLOBAL (W1 is 0.5 MB -> L2-resident; no LDS staging, no barriers
//          in the K-loop).  H -> 32 KB swizzled LDS (never hits HBM).
//   GEMM2: out = A1 + H @ W2^T + b2: A = H from LDS, B = W2 from L2,
//          barrier-free; residual read from A1 in LDS.
// Eliminates X2 (32 MB write + 64 MB read) and H (64 MB round-trip) HBM
// traffic plus two kernel launches.  acc = 32 f32/lane; 64 KB static LDS
// (r4-proven size); __launch_bounds__(512,4) caps VGPR at 128 (no spills).
// LDS chunk swizzle: phys16B-chunk = logical ^ (row&7) -- bank partners 8
// lanes apart (r1-proven-zero-conflict family).
//
// gemm_mixer/prep/ln1_norm_t: unchanged from round 7 (passed, 261 us).

#define B_ 64
#define T_ 512
#define C_ 512
#define TC_ (T_ * C_)
static_assert(TC_ == 262144, "");

typedef __attribute__((ext_vector_type(8))) short bf16x8;
typedef __attribute__((ext_vector_type(4))) float f32x4;

__device__ __forceinline__ unsigned short f2bf(float f) {
  union { float f; unsigned u; } v; v.f = f;
  unsigned r = v.u + 0x7FFF + ((v.u >> 16) & 1);   // RNE
  return (unsigned short)(r >> 16);
}
__device__ __forceinline__ float bf2f(unsigned short h) {
  union { unsigned u; float f; } v; v.u = ((unsigned)h) << 16; return v.f;
}

// async global -> LDS, 16 B per lane (global_load_lds_dwordx4)
__device__ __forceinline__ void load16_lds(const void* gsrc, void* ldst) {
  __builtin_amdgcn_global_load_lds(
      (const __attribute__((address_space(1))) unsigned int*)gsrc,
      (__attribute__((address_space(3))) unsigned int*)ldst,
      16, 0, 0);
}

// ------------- prep: weight conversion + ln1 stats (fused, independent) -------------
__global__ __launch_bounds__(256) void prep(
    const float* __restrict__ triM, const float* __restrict__ d1w,
    const float* __restrict__ d2w, unsigned short* __restrict__ Mb,
    unsigned short* __restrict__ W1b, unsigned short* __restrict__ W2b,
    const float* __restrict__ x, float* __restrict__ red) {
  if (blockIdx.x < 1024) {
    const int idx = blockIdx.x * 256 + threadIdx.x;   // 262144 total
    const int i = idx >> 9, j = idx & 511;
    Mb[idx]  = (j <= i) ? f2bf(triM[idx]) : (unsigned short)0;
    W1b[idx] = f2bf(d1w[idx]);
    W2b[idx] = f2bf(d2w[idx]);
    return;
  }
  const int bb = blockIdx.x - 1024;
  const int b = bb >> 4;
  const int s = bb & 15;
  const float4* p = (const float4*)(x + (size_t)b * TC_) + (size_t)s * 4096;
  float s1 = 0.f, s2 = 0.f;
  for (int i = threadIdx.x; i < 4096; i += 256) {
    float4 v = p[i];
    s1 += v.x + v.y + v.z + v.w;
    s2 += v.x * v.x + v.y * v.y + v.z * v.z + v.w * v.w;
  }
#pragma unroll
  for (int o = 32; o; o >>= 1) { s1 += __shfl_down(s1, o, 64); s2 += __shfl_down(s2, o, 64); }
  __shared__ float sm[8];
  const int w = threadIdx.x >> 6, lane = threadIdx.x & 63;
  if (lane == 0) { sm[w * 2] = s1; sm[w * 2 + 1] = s2; }
  __syncthreads();
  if (threadIdx.x == 0) {
    float a = 0.f, c = 0.f;
    for (int i = 0; i < 4; ++i) { a += sm[2 * i]; c += sm[2 * i + 1]; }
    atomicAdd(&red[b * 2], a);
    atomicAdd(&red[b * 2 + 1], c);
  }
}

// ------------- ln1 normalize + transposed bf16 write -------------
__global__ __launch_bounds__(256) void ln1_norm_t(
    const float* __restrict__ x, const float* __restrict__ w,
    const float* __restrict__ bvec, const float* __restrict__ red1,
    unsigned short* __restrict__ XnT) {
  __shared__ unsigned short tile[64][65];
  const int b = blockIdx.z;
  const int t0 = blockIdx.y * 64;
  const int c0 = blockIdx.x * 64;
  const float mu = red1[b * 2] * (1.f / TC_);
  const float rstd = rsqrtf(red1[b * 2 + 1] * (1.f / TC_) - mu * mu + 1e-5f);
  const int tid = threadIdx.x;
  const int r = tid >> 4;            // 0..15
  const int cg = (tid & 15) * 4;     // 0..60
#pragma unroll
  for (int rr = 0; rr < 4; ++rr) {
    const int t = t0 + rr * 16 + r;
    const float4 xv = *(const float4*)&x[((size_t)b * T_ + t) * C_ + c0 + cg];
    const float4 wv = *(const float4*)&w[(size_t)t * C_ + c0 + cg];
    const float4 bv = *(const float4*)&bvec[(size_t)t * C_ + c0 + cg];
    tile[rr * 16 + r][cg + 0] = f2bf((xv.x - mu) * rstd * wv.x + bv.x);
    tile[rr * 16 + r][cg + 1] = f2bf((xv.y - mu) * rstd * wv.y + bv.y);
    tile[rr * 16 + r][cg + 2] = f2bf((xv.z - mu) * rstd * wv.z + bv.z);
    tile[rr * 16 + r][cg + 3] = f2bf((xv.w - mu) * rstd * wv.w + bv.w);
  }
  __syncthreads();
  const int cl = tid >> 2;           // 0..63
  const int tg = (tid & 3) * 16;     // 0,16,32,48
  alignas(16) unsigned short tmp[16];
#pragma unroll
  for (int j = 0; j < 16; ++j) tmp[j] = tile[tg + j][cl];
  unsigned short* o = &XnT[((size_t)b * C_ + c0 + cl) * T_ + t0 + tg];
  *(uint4*)&o[0] = *(const uint4*)&tmp[0];
  *(uint4*)&o[8] = *(const uint4*)&tmp[8];
}

// ============ 128x128 GEMM mainloop (8 waves, BK=32, 32 KB dbuf) ============
__device__ __forceinline__ void stage_tile128(
    const unsigned short* __restrict__ Ag, const unsigned short* __restrict__ Bg,
    int k0, unsigned short* As, unsigned short* Bs, int tid) {
  const int row = tid >> 2;
  const int l = ((tid & 3) ^ ((row >> 1) & 3)) * 8;    // swizzled k-off (shorts)
  load16_lds(Ag + ((size_t)row << 9) + k0 + l, As + tid * 8);
  load16_lds(Bg + ((size_t)row << 9) + k0 + l, Bs + tid * 8);
}

__device__ __forceinline__ void mfma_tile128(
    const unsigned short* __restrict__ As, const unsigned short* __restrict__ Bs,
    int arow, int brow, int co, f32x4 acc[4][2]) {
  bf16x8 af[4], bfr[2];
#pragma unroll
  for (int m = 0; m < 4; ++m)
    af[m] = *(const bf16x8*)&As[arow + m * 512 + co];
#pragma unroll
  for (int n = 0; n < 2; ++n)
    bfr[n] = *(const bf16x8*)&Bs[brow + n * 512 + co];
  __builtin_amdgcn_s_setprio(1);
#pragma unroll
  for (int m = 0; m < 4; ++m)
#pragma unroll
    for (int n = 0; n < 2; ++n)
      acc[m][n] = __builtin_amdgcn_mfma_f32_16x16x32_bf16(af[m], bfr[n], acc[m][n], 0, 0, 0);
  __builtin_amdgcn_s_setprio(0);
}

__device__ __forceinline__ void gemm_mainloop128(
    const unsigned short* __restrict__ Ag, const unsigned short* __restrict__ Bg,
    int ktiles, unsigned short* lds, f32x4 acc[4][2], int tid) {
  const int lane = tid & 63;
  const int w = tid >> 6;
  const int wm = w >> 2, wn = w & 3;          // 2 x 4 wave grid
  const int m16 = lane & 15, quad = lane >> 4;
  unsigned short* A0 = lds;                   // 8 KB each
  unsigned short* B0 = lds + 4096;
  unsigned short* A1 = lds + 8192;
  unsigned short* B1 = lds + 12288;
  const int arow = (wm * 64 + m16) * 32;      // shorts (row stride 32)
  const int brow = (wn * 32 + m16) * 32;
  const int co = (quad ^ ((m16 >> 1) & 3)) * 8;   // read-side xor (r1-proven)
  stage_tile128(Ag, Bg, 0, A0, B0, tid);      // prologue: tile 0
  __syncthreads();
  for (int kt = 0; kt < ktiles; kt += 2) {
    stage_tile128(Ag, Bg, (kt + 1) * 32, A1, B1, tid);
    mfma_tile128(A0, B0, arow, brow, co, acc);
    __syncthreads();
    if (kt + 2 < ktiles)
      stage_tile128(Ag, Bg, (kt + 2) * 32, A0, B0, tid);
    mfma_tile128(A1, B1, arow, brow, co, acc);
    __syncthreads();
  }
}

// bijective XCD swizzle for 1024 blocks (1024 % 8 == 0)
__device__ __forceinline__ int xcd_swizzle_1024(int bid) {
  return ((bid & 7) << 7) | (bid >> 3);
}

// ---------------- mixer GEMM: Z = tril(M)@Xn + tri_b + inputs ----------------
__global__ __launch_bounds__(512, 4) void gemm_mixer(
    const unsigned short* __restrict__ Mb, const unsigned short* __restrict__ XnT,
    const float* __restrict__ trib, const float* __restrict__ inp,
    unsigned short* __restrict__ Z, float* __restrict__ red2) {
  __shared__ __align__(16) unsigned short lds[16384];   // 32 KB
  const int swz = xcd_swizzle_1024((int)blockIdx.x);
  const int b = swz >> 4;
  const int i0 = ((swz >> 2) & 3) * 128;
  const int c0 = (swz & 3) * 128;
  f32x4 acc[4][2];
#pragma unroll
  for (int m = 0; m < 4; ++m)
#pragma unroll
    for (int n = 0; n < 2; ++n) acc[m][n] = (f32x4){0.f, 0.f, 0.f, 0.f};
  // tril: rows < i0+128 only need k < i0+128
  gemm_mainloop128(Mb + (size_t)i0 * T_, XnT + (size_t)b * TC_ + (size_t)c0 * T_,
                   (i0 >> 5) + 4, lds, acc, (int)threadIdx.x);
  const int tid = threadIdx.x, lane = tid & 63, w = tid >> 6;
  const int wm = w >> 2, wn = w & 3, m16 = lane & 15, quad = lane >> 4;
  const int rbase = i0 + wm * 64, cbase = c0 + wn * 32;
  float s1 = 0.f, s2 = 0.f;
#pragma unroll
  for (int m = 0; m < 4; ++m) {
#pragma unroll
    for (int g = 0; g < 4; ++g) {
      const int i = rbase + m * 16 + quad * 4 + g;
      const float tb = trib[i];
      const float* inrow = &inp[((size_t)b * T_ + i) * C_];
      unsigned short* zrow = &Z[((size_t)b * T_ + i) * C_];
#pragma unroll
      for (int n = 0; n < 2; ++n) {
        const int ch = cbase + n * 16 + m16;
        const float v = acc[m][n][g] + tb + inrow[ch];
        zrow[ch] = f2bf(v);
        s1 += v; s2 += v * v;
      }
    }
  }
#pragma unroll
  for (int o = 32; o; o >>= 1) { s1 += __shfl_down(s1, o, 64); s2 += __shfl_down(s2, o, 64); }
  __shared__ float smf[16];
  if (lane == 0) { smf[w * 2] = s1; smf[w * 2 + 1] = s2; }
  __syncthreads();
  if (tid == 0) {
    float a = 0.f, c2 = 0.f;
    for (int i = 0; i < 8; ++i) { a += smf[2 * i]; c2 += smf[2 * i + 1]; }
    atomicAdd(&red2[b * 2], a);
    atomicAdd(&red2[b * 2 + 1], c2);
  }
}

// ======== fused MLP: out = X2 + gelu(X2@W1^T+b1)@W2^T + b2, X2 = ln2(Z) ========
// One block = one 32-row strip of one batch.  A1/H strips live in LDS;
// B operands (W1/W2, 0.5 MB each, L2-resident) are read as MFMA fragments
// directly from global -- K-loops have NO barriers and NO LDS writes.
// LDS layout [32 rows][512 shorts]; phys 16B-chunk = logical ^ (row & 7).
__global__ __launch_bounds__(512, 4) void gemm_mlp(
    const unsigned short* __restrict__ Z, const float* __restrict__ red2,
    const float* __restrict__ ln2w, const float* __restrict__ ln2b,
    const unsigned short* __restrict__ W1b, const float* __restrict__ d1b,
    const unsigned short* __restrict__ W2b, const float* __restrict__ d2b,
    float* __restrict__ out) {
  __shared__ __align__(16) unsigned short A1[32 * 512];   // 32 KB
  __shared__ __align__(16) unsigned short Hs[32 * 512];   // 32 KB
  const int bid = (int)blockIdx.x;
  const int b = bid >> 4;
  const int t0 = (bid & 15) * 32;
  const int tid = threadIdx.x;
  const float mu = red2[b * 2] * (1.f / TC_);
  const float rstd = rsqrtf(red2[b * 2 + 1] * (1.f / TC_) - mu * mu + 1e-5f);

  // ---- stage A1 = ln2(Z[strip]) into swizzled LDS (2048 chunks, 4/thread) ----
#pragma unroll
  for (int j = 0; j < 4; ++j) {
    const int c = tid + 512 * j;
    const int row = c >> 6;               // 0..31
    const int cin = c & 63;               // chunk within row
    const int col = cin * 8;
    const size_t g = ((size_t)b * T_ + t0 + row) * C_ + col;
    uint4 zp = *(const uint4*)&Z[g];
    const unsigned short* zs = (const unsigned short*)&zp;
    const float* wrow = &ln2w[(size_t)(t0 + row) * C_ + col];
    const float* brow = &ln2b[(size_t)(t0 + row) * C_ + col];
    alignas(16) unsigned short o8[8];
#pragma unroll
    for (int e = 0; e < 8; ++e)
      o8[e] = f2bf((bf2f(zs[e]) - mu) * rstd * wrow[e] + brow[e]);
    *(uint4*)&A1[row * 512 + ((cin ^ (row & 7)) * 8)] = *(const uint4*)&o8[0];
  }
  __syncthreads();

  const int lane = tid & 63, w = tid >> 6;
  const int m16 = lane & 15, quad = lane >> 4;
  const int cbase = w * 64;               // wave's 64-col n-range
  const int key = m16 & 7;                // LDS read-side xor (row&7 == m16&7)

  // ---- GEMM1: H = gelu(A1 @ W1^T + b1) -- barrier-free K-loop ----
  f32x4 acc[2][4];
#pragma unroll
  for (int m = 0; m < 2; ++m)
#pragma unroll
    for (int n = 0; n < 4; ++n) acc[m][n] = (f32x4){0.f, 0.f, 0.f, 0.f};
#pragma unroll 4
  for (int kt = 0; kt < 16; ++kt) {
    const int kq = kt * 4 + quad;         // 16B-chunk id 0..63
    bf16x8 af[2], bfr[4];
    af[0] = *(const bf16x8*)&A1[m16 * 512 + ((kq ^ key) * 8)];
    af[1] = *(const bf16x8*)&A1[(16 + m16) * 512 + ((kq ^ key) * 8)];
#pragma unroll
    for (int n = 0; n < 4; ++n)
      bfr[n] = *(const bf16x8*)&W1b[(size_t)(cbase + n * 16 + m16) * C_ + kq * 8];
    __builtin_amdgcn_s_setprio(1);
#pragma unroll
    for (int m = 0; m < 2; ++m)
#pragma unroll
      for (int n = 0; n < 4; ++n)
        acc[m][n] = __builtin_amdgcn_mfma_f32_16x16x32_bf16(af[m], bfr[n], acc[m][n], 0, 0, 0);
    __builtin_amdgcn_s_setprio(0);
  }
  // epilogue 1: gelu -> Hs (swizzled)
#pragma unroll
  for (int m = 0; m < 2; ++m) {
#pragma unroll
    for (int n = 0; n < 4; ++n) {
#pragma unroll
      for (int g = 0; g < 4; ++g) {
        const int row = m * 16 + quad * 4 + g;
        const int col = cbase + n * 16 + m16;
        const float v = acc[m][n][g] + d1b[col];
        const float gl = 0.5f * v * (1.0f + erff(v * 0.70710678118654752f));
        Hs[row * 512 + (((col >> 3) ^ (row & 7)) * 8) + (col & 7)] = f2bf(gl);
      }
    }
  }
  __syncthreads();

  // ---- GEMM2: out = A1 + Hs @ W2^T + b2 -- barrier-free K-loop ----
  f32x4 acc2[2][4];
#pragma unroll
  for (int m = 0; m < 2; ++m)
#pragma unroll
    for (int n = 0; n < 4; ++n) acc2[m][n] = (f32x4){0.f, 0.f, 0.f, 0.f};
#pragma unroll 4
  for (int kt = 0; kt < 16; ++kt) {
    const int kq = kt * 4 + quad;
    bf16x8 af[2], bfr[4];
    af[0] = *(const bf16x8*)&Hs[m16 * 512 + ((kq ^ key) * 8)];
    af[1] = *(const bf16x8*)&Hs[(16 + m16) * 512 + ((kq ^ key) * 8)];
#pragma unroll
    for (int n = 0; n < 4; ++n)
      bfr[n] = *(const bf16x8*)&W2b[(size_t)(cbase + n * 16 + m16) * C_ + kq * 8];
    __builtin_amdgcn_s_setprio(1);
#pragma unroll
    for (int m = 0; m < 2; ++m)
#pragma unroll
      for (int n = 0; n < 4; ++n)
        acc2[m][n] = __builtin_amdgcn_mfma_f32_16x16x32_bf16(af[m], bfr[n], acc2[m][n], 0, 0, 0);
    __builtin_amdgcn_s_setprio(0);
  }
  // epilogue 2: + bias + residual (A1 from LDS), fp32 store
#pragma unroll
  for (int m = 0; m < 2; ++m) {
#pragma unroll
    for (int n = 0; n < 4; ++n) {
#pragma unroll
      for (int g = 0; g < 4; ++g) {
        const int row = m * 16 + quad * 4 + g;
        const int col = cbase + n * 16 + m16;
        const float resid =
            bf2f(A1[row * 512 + (((col >> 3) ^ (row & 7)) * 8) + (col & 7)]);
        out[((size_t)b * T_ + t0 + row) * C_ + col] =
            acc2[m][n][g] + d2b[col] + resid;
      }
    }
  }
}

extern "C" void kernel_launch(void* const* d_in, const int* in_sizes, int n_in,
                              void* d_out, int out_size, void* d_ws, size_t ws_size,
                              hipStream_t stream) {
  const float* inp  = (const float*)d_in[0];
  const float* ln1w = (const float*)d_in[1];
  const float* ln1b = (const float*)d_in[2];
  const float* ln2w = (const float*)d_in[3];
  const float* ln2b = (const float*)d_in[4];
  const float* triM = (const float*)d_in[5];
  const float* trib = (const float*)d_in[6];
  const float* d1w  = (const float*)d_in[7];
  const float* d1b  = (const float*)d_in[8];
  const float* d2w  = (const float*)d_in[9];
  const float* d2b  = (const float*)d_in[10];
  float* out = (float*)d_out;

  char* ws = (char*)d_ws;
  float* red1 = (float*)ws;                         // 64*2 floats
  float* red2 = (float*)(ws + 512);                 // 64*2 floats
  unsigned short* Mb  = (unsigned short*)(ws + 1024);
  unsigned short* W1b = Mb + TC_;
  unsigned short* W2b = W1b + TC_;
  unsigned short* XnT = W2b + TC_;                  // [B][C][T] bf16
  unsigned short* Z   = XnT + (size_t)B_ * TC_;     // [B][T][C] bf16

  hipMemsetAsync(ws, 0, 1024, stream);
  prep<<<2048, 256, 0, stream>>>(triM, d1w, d2w, Mb, W1b, W2b, inp, red1);
  ln1_norm_t<<<dim3(8, 8, B_), 256, 0, stream>>>(inp, ln1w, ln1b, red1, XnT);
  gemm_mixer<<<1024, 512, 0, stream>>>(Mb, XnT, trib, inp, Z, red2);
  gemm_mlp<<<1024, 512, 0, stream>>>(Z, red2, ln2w, ln2b, W1b, d1b, W2b, d2b, out);
}

// Round 10
// 265.281 us; speedup vs baseline: 1.1559x; 1.1559x over previous
//
#include <hip/hip_runtime.h>
#include <hip/hip_bf16.h>
#include <math.h>

// Mixer2dTriU: B=64, T=512, C=512, fp32 in/out.
// 5 dispatches (was 8 in r7 @ 261 us; ~12-14 us launch/drain overhead each):
//   prep        conv weights (tril M, W1, W2, ln2 w/b -> bf16) + ln1 partial
//               stats (atomic-free) + zero red2        [replaces memset+conv+stats]
//   ln1_norm_t  sums 16 partials, normalize + transpose -> XnT
//   gemm_mixer  Z = tril(M)@Xn + tri_b + inp, fused ln2 stats (r7 body)
//   gemm_d1f    H = gelu(ln2(Z)@W1^T + b1) -- ln2 FUSED into the A-stage
//               (reg-staged transform, X2 never materialized)
//   gemm_d2f    out = ln2(Z) + H@W2^T + b2 -- residual ln2 recomputed in epilogue
// GEMM core (r7-proven): 128x128 tile, BK=32, 8 waves, 32 KB dbuf LDS,
// T3-minimal single barrier per K-iter, r1-proven-zero-conflict chunk swizzle
// ((row>>1)&3 key), setprio around MFMA, bijective XCD swizzle, (512,4).
// NO cooperative launch (killed the harness in r9), NO >64 KB LDS.

#define B_ 64
#define T_ 512
#define C_ 512
#define TC_ (T_ * C_)
static_assert(TC_ == 262144, "");

typedef __attribute__((ext_vector_type(8))) short bf16x8;
typedef __attribute__((ext_vector_type(4))) float f32x4;

__device__ __forceinline__ unsigned short f2bf(float f) {
  union { float f; unsigned u; } v; v.f = f;
  unsigned r = v.u + 0x7FFF + ((v.u >> 16) & 1);   // RNE
  return (unsigned short)(r >> 16);
}
__device__ __forceinline__ float bf2f(unsigned short h) {
  union { unsigned u; float f; } v; v.u = ((unsigned)h) << 16; return v.f;
}

// async global -> LDS, 16 B per lane (global_load_lds_dwordx4)
__device__ __forceinline__ void load16_lds(const void* gsrc, void* ldst) {
  __builtin_amdgcn_global_load_lds(
      (const __attribute__((address_space(1))) unsigned int*)gsrc,
      (__attribute__((address_space(3))) unsigned int*)ldst,
      16, 0, 0);
}

// ------------- prep: weights->bf16 + ln1 partial stats + zero red2 -------------
__global__ __launch_bounds__(256) void prep(
    const float* __restrict__ triM, const float* __restrict__ d1w,
    const float* __restrict__ d2w, const float* __restrict__ ln2w,
    const float* __restrict__ ln2b, unsigned short* __restrict__ Mb,
    unsigned short* __restrict__ W1b, unsigned short* __restrict__ W2b,
    unsigned short* __restrict__ Lw, unsigned short* __restrict__ Lb,
    const float* __restrict__ x, float* __restrict__ red1p,
    float* __restrict__ red2) {
  if (blockIdx.x < 1024) {
    if (blockIdx.x == 0 && threadIdx.x < 128) red2[threadIdx.x] = 0.f;
    const int idx = blockIdx.x * 256 + threadIdx.x;   // 262144 total
    const int i = idx >> 9, j = idx & 511;
    Mb[idx]  = (j <= i) ? f2bf(triM[idx]) : (unsigned short)0;
    W1b[idx] = f2bf(d1w[idx]);
    W2b[idx] = f2bf(d2w[idx]);
    Lw[idx]  = f2bf(ln2w[idx]);
    Lb[idx]  = f2bf(ln2b[idx]);
    return;
  }
  // ln1 stats: per-(batch,split) partials, NO atomics, NO memset dependency
  const int bb = blockIdx.x - 1024;               // = b*16 + s
  const int b = bb >> 4, s = bb & 15;
  const float4* p = (const float4*)(x + (size_t)b * TC_) + (size_t)s * 4096;
  float s1 = 0.f, s2 = 0.f;
  for (int i = threadIdx.x; i < 4096; i += 256) {
    float4 v = p[i];
    s1 += v.x + v.y + v.z + v.w;
    s2 += v.x * v.x + v.y * v.y + v.z * v.z + v.w * v.w;
  }
#pragma unroll
  for (int o = 32; o; o >>= 1) { s1 += __shfl_down(s1, o, 64); s2 += __shfl_down(s2, o, 64); }
  __shared__ float sm[8];
  const int w = threadIdx.x >> 6, lane = threadIdx.x & 63;
  if (lane == 0) { sm[w * 2] = s1; sm[w * 2 + 1] = s2; }
  __syncthreads();
  if (threadIdx.x == 0) {
    float a = 0.f, c = 0.f;
    for (int i = 0; i < 4; ++i) { a += sm[2 * i]; c += sm[2 * i + 1]; }
    red1p[bb * 2] = a;
    red1p[bb * 2 + 1] = c;
  }
}

// ------------- ln1 normalize + transposed bf16 write -------------
__global__ __launch_bounds__(256) void ln1_norm_t(
    const float* __restrict__ x, const float* __restrict__ w,
    const float* __restrict__ bvec, const float* __restrict__ red1p,
    unsigned short* __restrict__ XnT) {
  __shared__ unsigned short tile[64][65];
  const int b = blockIdx.z;
  const int t0 = blockIdx.y * 64;
  const int c0 = blockIdx.x * 64;
  float s1 = 0.f, s2 = 0.f;
#pragma unroll
  for (int i = 0; i < 16; ++i) {
    s1 += red1p[(b * 16 + i) * 2];
    s2 += red1p[(b * 16 + i) * 2 + 1];
  }
  const float mu = s1 * (1.f / TC_);
  const float rstd = rsqrtf(s2 * (1.f / TC_) - mu * mu + 1e-5f);
  const int tid = threadIdx.x;
  const int r = tid >> 4;            // 0..15
  const int cg = (tid & 15) * 4;     // 0..60
#pragma unroll
  for (int rr = 0; rr < 4; ++rr) {
    const int t = t0 + rr * 16 + r;
    const float4 xv = *(const float4*)&x[((size_t)b * T_ + t) * C_ + c0 + cg];
    const float4 wv = *(const float4*)&w[(size_t)t * C_ + c0 + cg];
    const float4 bv = *(const float4*)&bvec[(size_t)t * C_ + c0 + cg];
    tile[rr * 16 + r][cg + 0] = f2bf((xv.x - mu) * rstd * wv.x + bv.x);
    tile[rr * 16 + r][cg + 1] = f2bf((xv.y - mu) * rstd * wv.y + bv.y);
    tile[rr * 16 + r][cg + 2] = f2bf((xv.z - mu) * rstd * wv.z + bv.z);
    tile[rr * 16 + r][cg + 3] = f2bf((xv.w - mu) * rstd * wv.w + bv.w);
  }
  __syncthreads();
  const int cl = tid >> 2;           // 0..63
  const int tg = (tid & 3) * 16;     // 0,16,32,48
  alignas(16) unsigned short tmp[16];
#pragma unroll
  for (int j = 0; j < 16; ++j) tmp[j] = tile[tg + j][cl];
  unsigned short* o = &XnT[((size_t)b * C_ + c0 + cl) * T_ + t0 + tg];
  *(uint4*)&o[0] = *(const uint4*)&tmp[0];
  *(uint4*)&o[8] = *(const uint4*)&tmp[8];
}

// ============ 128x128 GEMM core (8 waves, BK=32, 32 KB dbuf) -- r7-proven ============
__device__ __forceinline__ void stage_tile128(
    const unsigned short* __restrict__ Ag, const unsigned short* __restrict__ Bg,
    int k0, unsigned short* As, unsigned short* Bs, int tid) {
  const int row = tid >> 2;
  const int l = ((tid & 3) ^ ((row >> 1) & 3)) * 8;    // swizzled k-off (shorts)
  load16_lds(Ag + ((size_t)row << 9) + k0 + l, As + tid * 8);
  load16_lds(Bg + ((size_t)row << 9) + k0 + l, Bs + tid * 8);
}

__device__ __forceinline__ void stage_b128(
    const unsigned short* __restrict__ Bg, int k0, unsigned short* Bs, int tid) {
  const int row = tid >> 2;
  const int l = ((tid & 3) ^ ((row >> 1) & 3)) * 8;
  load16_lds(Bg + ((size_t)row << 9) + k0 + l, Bs + tid * 8);
}

__device__ __forceinline__ void mfma_tile128(
    const unsigned short* __restrict__ As, const unsigned short* __restrict__ Bs,
    int arow, int brow, int co, f32x4 acc[4][2]) {
  bf16x8 af[4], bfr[2];
#pragma unroll
  for (int m = 0; m < 4; ++m)
    af[m] = *(const bf16x8*)&As[arow + m * 512 + co];
#pragma unroll
  for (int n = 0; n < 2; ++n)
    bfr[n] = *(const bf16x8*)&Bs[brow + n * 512 + co];
  __builtin_amdgcn_s_setprio(1);
#pragma unroll
  for (int m = 0; m < 4; ++m)
#pragma unroll
    for (int n = 0; n < 2; ++n)
      acc[m][n] = __builtin_amdgcn_mfma_f32_16x16x32_bf16(af[m], bfr[n], acc[m][n], 0, 0, 0);
  __builtin_amdgcn_s_setprio(0);
}

__device__ __forceinline__ void gemm_mainloop128(
    const unsigned short* __restrict__ Ag, const unsigned short* __restrict__ Bg,
    int ktiles, unsigned short* lds, f32x4 acc[4][2], int tid) {
  const int lane = tid & 63;
  const int w = tid >> 6;
  const int wm = w >> 2, wn = w & 3;          // 2 x 4 wave grid
  const int m16 = lane & 15, quad = lane >> 4;
  unsigned short* A0 = lds;                   // 8 KB each
  unsigned short* B0 = lds + 4096;
  unsigned short* A1 = lds + 8192;
  unsigned short* B1 = lds + 12288;
  const int arow = (wm * 64 + m16) * 32;
  const int brow = (wn * 32 + m16) * 32;
  const int co = (quad ^ ((m16 >> 1) & 3)) * 8;
  stage_tile128(Ag, Bg, 0, A0, B0, tid);
  __syncthreads();
  for (int kt = 0; kt < ktiles; kt += 2) {
    stage_tile128(Ag, Bg, (kt + 1) * 32, A1, B1, tid);
    mfma_tile128(A0, B0, arow, brow, co, acc);
    __syncthreads();
    if (kt + 2 < ktiles)
      stage_tile128(Ag, Bg, (kt + 2) * 32, A0, B0, tid);
    mfma_tile128(A1, B1, arow, brow, co, acc);
    __syncthreads();
  }
}

// bijective XCD swizzle for 1024 blocks (1024 % 8 == 0)
__device__ __forceinline__ int xcd_swizzle_1024(int bid) {
  return ((bid & 7) << 7) | (bid >> 3);
}

// ---------------- mixer GEMM: Z = tril(M)@Xn + tri_b + inputs (r7 body) ----------------
__global__ __launch_bounds__(512, 4) void gemm_mixer(
    const unsigned short* __restrict__ Mb, const unsigned short* __restrict__ XnT,
    const float* __restrict__ trib, const float* __restrict__ inp,
    unsigned short* __restrict__ Z, float* __restrict__ red2) {
  __shared__ __align__(16) unsigned short lds[16384];   // 32 KB
  const int swz = xcd_swizzle_1024((int)blockIdx.x);
  const int b = swz >> 4;
  const int i0 = ((swz >> 2) & 3) * 128;
  const int c0 = (swz & 3) * 128;
  f32x4 acc[4][2];
#pragma unroll
  for (int m = 0; m < 4; ++m)
#pragma unroll
    for (int n = 0; n < 2; ++n) acc[m][n] = (f32x4){0.f, 0.f, 0.f, 0.f};
  // tril: rows < i0+128 only need k < i0+128
  gemm_mainloop128(Mb + (size_t)i0 * T_, XnT + (size_t)b * TC_ + (size_t)c0 * T_,
                   (i0 >> 5) + 4, lds, acc, (int)threadIdx.x);
  const int tid = threadIdx.x, lane = tid & 63, w = tid >> 6;
  const int wm = w >> 2, wn = w & 3, m16 = lane & 15, quad = lane >> 4;
  const int rbase = i0 + wm * 64, cbase = c0 + wn * 32;
  float s1 = 0.f, s2 = 0.f;
#pragma unroll
  for (int m = 0; m < 4; ++m) {
#pragma unroll
    for (int g = 0; g < 4; ++g) {
      const int i = rbase + m * 16 + quad * 4 + g;
      const float tb = trib[i];
      const float* inrow = &inp[((size_t)b * T_ + i) * C_];
      unsigned short* zrow = &Z[((size_t)b * T_ + i) * C_];
#pragma unroll
      for (int n = 0; n < 2; ++n) {
        const int ch = cbase + n * 16 + m16;
        const float v = acc[m][n][g] + tb + inrow[ch];
        zrow[ch] = f2bf(v);
        s1 += v; s2 += v * v;
      }
    }
  }
#pragma unroll
  for (int o = 32; o; o >>= 1) { s1 += __shfl_down(s1, o, 64); s2 += __shfl_down(s2, o, 64); }
  __shared__ float smf[16];
  if (lane == 0) { smf[w * 2] = s1; smf[w * 2 + 1] = s2; }
  __syncthreads();
  if (tid == 0) {
    float a = 0.f, c2 = 0.f;
    for (int i = 0; i < 8; ++i) { a += smf[2 * i]; c2 += smf[2 * i + 1]; }
    atomicAdd(&red2[b * 2], a);
    atomicAdd(&red2[b * 2 + 1], c2);
  }
}

// -------- MLP GEMM 1 (ln2 fused): H = gelu(ln2(Z) @ W1^T + b1) --------
// A-stage is reg-staged: load Z chunk + bf16 ln2 w/b, transform, ds_write to
// the NON-read buffer before the single barrier (same hazard structure as the
// proven loop).  mu/rstd are block-uniform (128-row tile within one batch).
__global__ __launch_bounds__(512, 4) void gemm_d1f(
    const unsigned short* __restrict__ Z, const float* __restrict__ red2,
    const unsigned short* __restrict__ Lw, const unsigned short* __restrict__ Lb,
    const unsigned short* __restrict__ W1b, const float* __restrict__ d1b,
    unsigned short* __restrict__ H) {
  __shared__ __align__(16) unsigned short lds[16384];
  const int swz = xcd_swizzle_1024((int)blockIdx.x);
  const int i0 = (swz & 255) * 128;
  const int n0 = (swz >> 8) * 128;
  const int tid = (int)threadIdx.x;
  const int batch = i0 >> 9;
  const float mu = red2[batch * 2] * (1.f / TC_);
  const float rstd = rsqrtf(red2[batch * 2 + 1] * (1.f / TC_) - mu * mu + 1e-5f);

  const int srow = tid >> 2;
  const int sl = ((tid & 3) ^ ((srow >> 1) & 3)) * 8;
  const int t = (i0 + srow) & 511;
  const unsigned short* zrow = Z + ((size_t)(i0 + srow) << 9);
  const unsigned short* wrow = Lw + ((size_t)t << 9);
  const unsigned short* brw  = Lb + ((size_t)t << 9);
  const unsigned short* Bg = W1b + (size_t)n0 * C_;

  unsigned short* A0 = lds;
  unsigned short* B0 = lds + 4096;
  unsigned short* A1 = lds + 8192;
  unsigned short* B1 = lds + 12288;

  f32x4 acc[4][2];
#pragma unroll
  for (int m = 0; m < 4; ++m)
#pragma unroll
    for (int n = 0; n < 2; ++n) acc[m][n] = (f32x4){0.f, 0.f, 0.f, 0.f};
  const int lane = tid & 63, wv = tid >> 6;
  const int wm = wv >> 2, wn = wv & 3, m16 = lane & 15, quad = lane >> 4;
  const int arow = (wm * 64 + m16) * 32;
  const int brow_l = (wn * 32 + m16) * 32;
  const int co = (quad ^ ((m16 >> 1) & 3)) * 8;

  uint4 zp, wp, bp;
  // prologue: A tile 0 (load+transform+write), B tile 0 (async)
  zp = *(const uint4*)&zrow[sl];
  wp = *(const uint4*)&wrow[sl];
  bp = *(const uint4*)&brw[sl];
  {
    const unsigned short* zs = (const unsigned short*)&zp;
    const unsigned short* ws = (const unsigned short*)&wp;
    const unsigned short* bs = (const unsigned short*)&bp;
    alignas(16) unsigned short o8[8];
#pragma unroll
    for (int e = 0; e < 8; ++e)
      o8[e] = f2bf((bf2f(zs[e]) - mu) * rstd * bf2f(ws[e]) + bf2f(bs[e]));
    *(uint4*)&A0[tid * 8] = *(const uint4*)&o8[0];
  }
  stage_b128(Bg, 0, B0, tid);
  __syncthreads();
  for (int kt = 0; kt < 16; ++kt) {
    unsigned short* Ac = (kt & 1) ? A1 : A0;
    unsigned short* Bc = (kt & 1) ? B1 : B0;
    unsigned short* An = (kt & 1) ? A0 : A1;
    unsigned short* Bn = (kt & 1) ? B0 : B1;
    const int k1 = (kt + 1) * 32;
    if (kt + 1 < 16) {                 // issue next-tile loads before compute
      zp = *(const uint4*)&zrow[k1 + sl];
      wp = *(const uint4*)&wrow[k1 + sl];
      bp = *(const uint4*)&brw[k1 + sl];
      stage_b128(Bg, k1, Bn, tid);
    }
    mfma_tile128(Ac, Bc, arow, brow_l, co, acc);
    if (kt + 1 < 16) {                 // transform+write to NON-read buffer
      const unsigned short* zs = (const unsigned short*)&zp;
      const unsigned short* ws = (const unsigned short*)&wp;
      const unsigned short* bs = (const unsigned short*)&bp;
      alignas(16) unsigned short o8[8];
#pragma unroll
      for (int e = 0; e < 8; ++e)
        o8[e] = f2bf((bf2f(zs[e]) - mu) * rstd * bf2f(ws[e]) + bf2f(bs[e]));
      *(uint4*)&An[tid * 8] = *(const uint4*)&o8[0];
    }
    __syncthreads();                   // one barrier per K-iter
  }
  const int rbase = i0 + wm * 64, cbase = n0 + wn * 32;
#pragma unroll
  for (int m = 0; m < 4; ++m) {
#pragma unroll
    for (int g = 0; g < 4; ++g) {
      const int row = rbase + m * 16 + quad * 4 + g;
#pragma unroll
      for (int n = 0; n < 2; ++n) {
        const int col = cbase + n * 16 + m16;
        const float v = acc[m][n][g] + d1b[col];
        const float gl = 0.5f * v * (1.0f + erff(v * 0.70710678118654752f));
        H[(size_t)row * C_ + col] = f2bf(gl);
      }
    }
  }
}

// -------- MLP GEMM 2 (ln2 fused residual): out = ln2(Z) + H @ W2^T + b2 --------
__global__ __launch_bounds__(512, 4) void gemm_d2f(
    const unsigned short* __restrict__ H, const unsigned short* __restrict__ W2b,
    const float* __restrict__ d2b, const unsigned short* __restrict__ Z,
    const float* __restrict__ red2, const unsigned short* __restrict__ Lw,
    const unsigned short* __restrict__ Lb, float* __restrict__ out) {
  __shared__ __align__(16) unsigned short lds[16384];
  const int swz = xcd_swizzle_1024((int)blockIdx.x);
  const int i0 = (swz & 255) * 128;
  const int n0 = (swz >> 8) * 128;
  const int batch = i0 >> 9;
  const float mu = red2[batch * 2] * (1.f / TC_);
  const float rstd = rsqrtf(red2[batch * 2 + 1] * (1.f / TC_) - mu * mu + 1e-5f);
  f32x4 acc[4][2];
#pragma unroll
  for (int m = 0; m < 4; ++m)
#pragma unroll
    for (int n = 0; n < 2; ++n) acc[m][n] = (f32x4){0.f, 0.f, 0.f, 0.f};
  gemm_mainloop128(H + (size_t)i0 * C_, W2b + (size_t)n0 * C_, 16, lds, acc,
                   (int)threadIdx.x);
  const int tid = threadIdx.x, lane = tid & 63, w = tid >> 6;
  const int wm = w >> 2, wn = w & 3, m16 = lane & 15, quad = lane >> 4;
  const int rbase = i0 + wm * 64, cbase = n0 + wn * 32;
#pragma unroll
  for (int m = 0; m < 4; ++m) {
#pragma unroll
    for (int g = 0; g < 4; ++g) {
      const int row = rbase + m * 16 + quad * 4 + g;
      const int t = row & 511;
#pragma unroll
      for (int n = 0; n < 2; ++n) {
        const int col = cbase + n * 16 + m16;
        const float resid =
            (bf2f(Z[(size_t)row * C_ + col]) - mu) * rstd *
                bf2f(Lw[(size_t)t * C_ + col]) +
            bf2f(Lb[(size_t)t * C_ + col]);
        out[(size_t)row * C_ + col] = acc[m][n][g] + d2b[col] + resid;
      }
    }
  }
}

extern "C" void kernel_launch(void* const* d_in, const int* in_sizes, int n_in,
                              void* d_out, int out_size, void* d_ws, size_t ws_size,
                              hipStream_t stream) {
  const float* inp  = (const float*)d_in[0];
  const float* ln1w = (const float*)d_in[1];
  const float* ln1b = (const float*)d_in[2];
  const float* ln2w = (const float*)d_in[3];
  const float* ln2b = (const float*)d_in[4];
  const float* triM = (const float*)d_in[5];
  const float* trib = (const float*)d_in[6];
  const float* d1w  = (const float*)d_in[7];
  const float* d1b  = (const float*)d_in[8];
  const float* d2w  = (const float*)d_in[9];
  const float* d2b  = (const float*)d_in[10];
  float* out = (float*)d_out;

  char* ws = (char*)d_ws;
  float* red1p = (float*)ws;                        // 1024*2 floats (8 KB)
  float* red2  = (float*)(ws + 8192);               // 64*2 floats
  unsigned short* Mb  = (unsigned short*)(ws + 16384);
  unsigned short* W1b = Mb + TC_;
  unsigned short* W2b = W1b + TC_;
  unsigned short* Lw  = W2b + TC_;                  // ln2 weight bf16
  unsigned short* Lb  = Lw + TC_;                   // ln2 bias bf16
  unsigned short* XnT = Lb + TC_;                   // [B][C][T] bf16
  unsigned short* Z   = XnT + (size_t)B_ * TC_;     // [B][T][C] bf16
  unsigned short* H   = Z + (size_t)B_ * TC_;       // [B*T][C] bf16

  prep<<<2048, 256, 0, stream>>>(triM, d1w, d2w, ln2w, ln2b, Mb, W1b, W2b,
                                 Lw, Lb, inp, red1p, red2);
  ln1_norm_t<<<dim3(8, 8, B_), 256, 0, stream>>>(inp, ln1w, ln1b, red1p, XnT);
  gemm_mixer<<<1024, 512, 0, stream>>>(Mb, XnT, trib, inp, Z, red2);
  gemm_d1f<<<1024, 512, 0, stream>>>(Z, red2, Lw, Lb, W1b, d1b, H);
  gemm_d2f<<<1024, 512, 0, stream>>>(H, W2b, d2b, Z, red2, Lw, Lb, out);
}

// Round 11
// 248.120 us; speedup vs baseline: 1.2358x; 1.0692x over previous
//
#include <hip/hip_runtime.h>
#include <hip/hip_bf16.h>
#include <math.h>

// Mixer2dTriU: B=64, T=512, C=512, fp32 in/out.
// 6 dispatches:
//   prep        conv weights (tril M, W1, W2 -> bf16) + ln1 partial stats
//               (atomic-free red1p) + zero red2       [no memset dispatch]
//   ln1_norm_t  sum 16 partials, normalize + transpose -> XnT
//   gemm_mixer  Z = tril(M)@Xn + tri_b + inp, fused ln2 stats
//   ln2_norm    X2 = ln2(Z) bf16                      [r7 body, fusion reverted]
//   gemm_d1     H = gelu(X2@W1^T + b1)                [r7 body]
//   gemm_d2     out = X2 + H@W2^T + b2                [r7 body]
//
// GEMM core: 128x128 tile, **BK=64 -> 8 K-iterations** (halved from 16: the
// r0/r4/r7 data shows d1 time ~ 2.6-3.0 us per K-iteration regardless of tile
// size / schedule / occupancy -- iteration count is the lever), 8 waves,
// 64 KB double-buffered LDS (r4-proven static size), T3-minimal single
// barrier per iter via global_load_lds (r7-proven hazard structure).
// Chunk swizzle: phys 16B-chunk = logical ^ (row&7) (r6-measured 0 conflicts;
// bank partners 8 lanes apart = free 2-way).  setprio around MFMA; bijective
// XCD swizzle; __launch_bounds__(512,4) (2 blocks/CU = the 64 KB LDS limit).

#define B_ 64
#define T_ 512
#define C_ 512
#define TC_ (T_ * C_)
static_assert(TC_ == 262144, "");

typedef __attribute__((ext_vector_type(8))) short bf16x8;
typedef __attribute__((ext_vector_type(4))) float f32x4;

__device__ __forceinline__ unsigned short f2bf(float f) {
  union { float f; unsigned u; } v; v.f = f;
  unsigned r = v.u + 0x7FFF + ((v.u >> 16) & 1);   // RNE
  return (unsigned short)(r >> 16);
}
__device__ __forceinline__ float bf2f(unsigned short h) {
  union { unsigned u; float f; } v; v.u = ((unsigned)h) << 16; return v.f;
}

// async global -> LDS, 16 B per lane (global_load_lds_dwordx4)
__device__ __forceinline__ void load16_lds(const void* gsrc, void* ldst) {
  __builtin_amdgcn_global_load_lds(
      (const __attribute__((address_space(1))) unsigned int*)gsrc,
      (__attribute__((address_space(3))) unsigned int*)ldst,
      16, 0, 0);
}

// ------------- prep: weights->bf16 + ln1 partial stats + zero red2 -------------
__global__ __launch_bounds__(256) void prep(
    const float* __restrict__ triM, const float* __restrict__ d1w,
    const float* __restrict__ d2w, unsigned short* __restrict__ Mb,
    unsigned short* __restrict__ W1b, unsigned short* __restrict__ W2b,
    const float* __restrict__ x, float* __restrict__ red1p,
    float* __restrict__ red2) {
  if (blockIdx.x < 1024) {
    if (blockIdx.x == 0 && threadIdx.x < 128) red2[threadIdx.x] = 0.f;
    const int idx = blockIdx.x * 256 + threadIdx.x;   // 262144 total
    const int i = idx >> 9, j = idx & 511;
    Mb[idx]  = (j <= i) ? f2bf(triM[idx]) : (unsigned short)0;
    W1b[idx] = f2bf(d1w[idx]);
    W2b[idx] = f2bf(d2w[idx]);
    return;
  }
  // ln1 stats: per-(batch,split) partials, NO atomics, NO memset dependency
  const int bb = blockIdx.x - 1024;               // = b*16 + s
  const int b = bb >> 4, s = bb & 15;
  const float4* p = (const float4*)(x + (size_t)b * TC_) + (size_t)s * 4096;
  float s1 = 0.f, s2 = 0.f;
  for (int i = threadIdx.x; i < 4096; i += 256) {
    float4 v = p[i];
    s1 += v.x + v.y + v.z + v.w;
    s2 += v.x * v.x + v.y * v.y + v.z * v.z + v.w * v.w;
  }
#pragma unroll
  for (int o = 32; o; o >>= 1) { s1 += __shfl_down(s1, o, 64); s2 += __shfl_down(s2, o, 64); }
  __shared__ float sm[8];
  const int w = threadIdx.x >> 6, lane = threadIdx.x & 63;
  if (lane == 0) { sm[w * 2] = s1; sm[w * 2 + 1] = s2; }
  __syncthreads();
  if (threadIdx.x == 0) {
    float a = 0.f, c = 0.f;
    for (int i = 0; i < 4; ++i) { a += sm[2 * i]; c += sm[2 * i + 1]; }
    red1p[bb * 2] = a;
    red1p[bb * 2 + 1] = c;
  }
}

// ------------- ln1 normalize + transposed bf16 write -------------
__global__ __launch_bounds__(256) void ln1_norm_t(
    const float* __restrict__ x, const float* __restrict__ w,
    const float* __restrict__ bvec, const float* __restrict__ red1p,
    unsigned short* __restrict__ XnT) {
  __shared__ unsigned short tile[64][65];
  const int b = blockIdx.z;
  const int t0 = blockIdx.y * 64;
  const int c0 = blockIdx.x * 64;
  float s1 = 0.f, s2 = 0.f;
#pragma unroll
  for (int i = 0; i < 16; ++i) {
    s1 += red1p[(b * 16 + i) * 2];
    s2 += red1p[(b * 16 + i) * 2 + 1];
  }
  const float mu = s1 * (1.f / TC_);
  const float rstd = rsqrtf(s2 * (1.f / TC_) - mu * mu + 1e-5f);
  const int tid = threadIdx.x;
  const int r = tid >> 4;            // 0..15
  const int cg = (tid & 15) * 4;     // 0..60
#pragma unroll
  for (int rr = 0; rr < 4; ++rr) {
    const int t = t0 + rr * 16 + r;
    const float4 xv = *(const float4*)&x[((size_t)b * T_ + t) * C_ + c0 + cg];
    const float4 wv = *(const float4*)&w[(size_t)t * C_ + c0 + cg];
    const float4 bv = *(const float4*)&bvec[(size_t)t * C_ + c0 + cg];
    tile[rr * 16 + r][cg + 0] = f2bf((xv.x - mu) * rstd * wv.x + bv.x);
    tile[rr * 16 + r][cg + 1] = f2bf((xv.y - mu) * rstd * wv.y + bv.y);
    tile[rr * 16 + r][cg + 2] = f2bf((xv.z - mu) * rstd * wv.z + bv.z);
    tile[rr * 16 + r][cg + 3] = f2bf((xv.w - mu) * rstd * wv.w + bv.w);
  }
  __syncthreads();
  const int cl = tid >> 2;           // 0..63
  const int tg = (tid & 3) * 16;     // 0,16,32,48
  alignas(16) unsigned short tmp[16];
#pragma unroll
  for (int j = 0; j < 16; ++j) tmp[j] = tile[tg + j][cl];
  unsigned short* o = &XnT[((size_t)b * C_ + c0 + cl) * T_ + t0 + tg];
  *(uint4*)&o[0] = *(const uint4*)&tmp[0];
  *(uint4*)&o[8] = *(const uint4*)&tmp[8];
}

// ============ 128x128 GEMM mainloop, BK=64, 8 waves, 64 KB dbuf ============
// A rows = C rows (at i0), B rows = C cols (at n0); both ld = 512 shorts.
// LDS tile [128 rows][64 shorts = 8 chunks of 16B].  Physical chunk p of row
// holds logical chunk p ^ (row & 7) (r6-measured: 0 bank conflicts; same-bank
// partners are lanes (m16, m16+8) -> free 2-way).  Stage: linear LDS dest
// (global_load_lds requirement), inverse-permuted global source (involution).
__device__ __forceinline__ void stage_tile64(
    const unsigned short* __restrict__ Ag, const unsigned short* __restrict__ Bg,
    int k0, unsigned short* As, unsigned short* Bs, int tid) {
#pragma unroll
  for (int j = 0; j < 2; ++j) {
    const int c = tid + 512 * j;               // 0..1023, 16B chunks
    const int row = c >> 3;
    const int l = ((c & 7) ^ (row & 7)) * 8;   // swizzled k-offset (shorts)
    load16_lds(Ag + ((size_t)row << 9) + k0 + l, As + c * 8);
    load16_lds(Bg + ((size_t)row << 9) + k0 + l, Bs + c * 8);
  }
}

// one K-tile (K=64): 2 k-slices x (4 M x 2 N) 16x16x32 per wave
__device__ __forceinline__ void mfma_tile64(
    const unsigned short* __restrict__ As, const unsigned short* __restrict__ Bs,
    int arow, int brow, int quad, int xk, f32x4 acc[4][2]) {
#pragma unroll
  for (int ks = 0; ks < 2; ++ks) {
    const int co = (((ks * 4 + quad) ^ xk) * 8);
    bf16x8 af[4], bfr[2];
#pragma unroll
    for (int m = 0; m < 4; ++m)
      af[m] = *(const bf16x8*)&As[arow + m * 1024 + co];
#pragma unroll
    for (int n = 0; n < 2; ++n)
      bfr[n] = *(const bf16x8*)&Bs[brow + n * 1024 + co];
    __builtin_amdgcn_s_setprio(1);
#pragma unroll
    for (int m = 0; m < 4; ++m)
#pragma unroll
      for (int n = 0; n < 2; ++n)
        acc[m][n] = __builtin_amdgcn_mfma_f32_16x16x32_bf16(af[m], bfr[n], acc[m][n], 0, 0, 0);
    __builtin_amdgcn_s_setprio(0);
  }
}

__device__ __forceinline__ void gemm_mainloop64(
    const unsigned short* __restrict__ Ag, const unsigned short* __restrict__ Bg,
    int ktiles,                               // even (2..8)
    unsigned short* lds, f32x4 acc[4][2], int tid) {
  const int lane = tid & 63;
  const int w = tid >> 6;
  const int wm = w >> 2, wn = w & 3;          // 2 x 4 wave grid
  const int m16 = lane & 15, quad = lane >> 4;
  unsigned short* A0 = lds;                   // 16 KB each
  unsigned short* B0 = lds + 8192;
  unsigned short* A1 = lds + 16384;
  unsigned short* B1 = lds + 24576;
  const int arow = (wm * 64 + m16) * 64;      // shorts (row stride 64)
  const int brow = (wn * 32 + m16) * 64;
  const int xk = m16 & 7;                     // read-side xor key
  stage_tile64(Ag, Bg, 0, A0, B0, tid);       // prologue: tile 0
  __syncthreads();
  for (int kt = 0; kt < ktiles; kt += 2) {
    // even: prefetch kt+1 -> (A1,B1), compute (A0,B0), drain after MFMA
    stage_tile64(Ag, Bg, (kt + 1) * 64, A1, B1, tid);
    mfma_tile64(A0, B0, arow, brow, quad, xk, acc);
    __syncthreads();
    // odd: prefetch kt+2 -> (A0,B0), compute (A1,B1)
    if (kt + 2 < ktiles)
      stage_tile64(Ag, Bg, (kt + 2) * 64, A0, B0, tid);
    mfma_tile64(A1, B1, arow, brow, quad, xk, acc);
    __syncthreads();
  }
}

// bijective XCD swizzle for 1024 blocks (1024 % 8 == 0)
__device__ __forceinline__ int xcd_swizzle_1024(int bid) {
  return ((bid & 7) << 7) | (bid >> 3);
}

// ---------------- mixer GEMM: Z = tril(M)@Xn + tri_b + inputs ----------------
__global__ __launch_bounds__(512, 4) void gemm_mixer(
    const unsigned short* __restrict__ Mb, const unsigned short* __restrict__ XnT,
    const float* __restrict__ trib, const float* __restrict__ inp,
    unsigned short* __restrict__ Z, float* __restrict__ red2) {
  __shared__ __align__(16) unsigned short lds[32768];   // 64 KB
  const int swz = xcd_swizzle_1024((int)blockIdx.x);
  const int b = swz >> 4;
  const int i0 = ((swz >> 2) & 3) * 128;
  const int c0 = (swz & 3) * 128;
  f32x4 acc[4][2];
#pragma unroll
  for (int m = 0; m < 4; ++m)
#pragma unroll
    for (int n = 0; n < 2; ++n) acc[m][n] = (f32x4){0.f, 0.f, 0.f, 0.f};
  // tril: rows < i0+128 only need k < i0+128 -> ktiles = (i0+128)/64 (even)
  gemm_mainloop64(Mb + (size_t)i0 * T_, XnT + (size_t)b * TC_ + (size_t)c0 * T_,
                  (i0 >> 6) + 2, lds, acc, (int)threadIdx.x);
  const int tid = threadIdx.x, lane = tid & 63, w = tid >> 6;
  const int wm = w >> 2, wn = w & 3, m16 = lane & 15, quad = lane >> 4;
  const int rbase = i0 + wm * 64, cbase = c0 + wn * 32;
  float s1 = 0.f, s2 = 0.f;
#pragma unroll
  for (int m = 0; m < 4; ++m) {
#pragma unroll
    for (int g = 0; g < 4; ++g) {
      const int i = rbase + m * 16 + quad * 4 + g;
      const float tb = trib[i];
      const float* inrow = &inp[((size_t)b * T_ + i) * C_];
      unsigned short* zrow = &Z[((size_t)b * T_ + i) * C_];
#pragma unroll
      for (int n = 0; n < 2; ++n) {
        const int ch = cbase + n * 16 + m16;
        const float v = acc[m][n][g] + tb + inrow[ch];
        zrow[ch] = f2bf(v);
        s1 += v; s2 += v * v;
      }
    }
  }
#pragma unroll
  for (int o = 32; o; o >>= 1) { s1 += __shfl_down(s1, o, 64); s2 += __shfl_down(s2, o, 64); }
  __shared__ float smf[16];
  if (lane == 0) { smf[w * 2] = s1; smf[w * 2 + 1] = s2; }
  __syncthreads();
  if (tid == 0) {
    float a = 0.f, c2 = 0.f;
    for (int i = 0; i < 8; ++i) { a += smf[2 * i]; c2 += smf[2 * i + 1]; }
    atomicAdd(&red2[b * 2], a);
    atomicAdd(&red2[b * 2 + 1], c2);
  }
}

// ---------------- ln2 normalize ----------------
__global__ __launch_bounds__(256) void ln2_norm(
    const unsigned short* __restrict__ Z, const float* __restrict__ red2,
    const float* __restrict__ w, const float* __restrict__ bvec,
    unsigned short* __restrict__ X2) {
  const size_t e = ((size_t)blockIdx.x * 256 + threadIdx.x) * 8;
  const int b = (int)(e >> 18);
  const int tc = (int)(e & (TC_ - 1));
  const float mu = red2[b * 2] * (1.f / TC_);
  const float rstd = rsqrtf(red2[b * 2 + 1] * (1.f / TC_) - mu * mu + 1e-5f);
  uint4 zp = *(const uint4*)&Z[e];
  const unsigned short* zs = (const unsigned short*)&zp;
  alignas(16) float wv[8], bb[8];
  *(float4*)&wv[0] = *(const float4*)&w[tc];
  *(float4*)&wv[4] = *(const float4*)&w[tc + 4];
  *(float4*)&bb[0] = *(const float4*)&bvec[tc];
  *(float4*)&bb[4] = *(const float4*)&bvec[tc + 4];
  alignas(16) unsigned short o[8];
#pragma unroll
  for (int j = 0; j < 8; ++j)
    o[j] = f2bf((bf2f(zs[j]) - mu) * rstd * wv[j] + bb[j]);
  *(uint4*)&X2[e] = *(const uint4*)&o[0];
}

// ---------------- MLP GEMM 1: H = gelu(X2 @ W1^T + b1) ----------------
__global__ __launch_bounds__(512, 4) void gemm_d1(
    const unsigned short* __restrict__ X2, const unsigned short* __restrict__ W1b,
    const float* __restrict__ d1b, unsigned short* __restrict__ H) {
  __shared__ __align__(16) unsigned short lds[32768];
  const int swz = xcd_swizzle_1024((int)blockIdx.x);
  const int i0 = (swz & 255) * 128;
  const int n0 = (swz >> 8) * 128;
  f32x4 acc[4][2];
#pragma unroll
  for (int m = 0; m < 4; ++m)
#pragma unroll
    for (int n = 0; n < 2; ++n) acc[m][n] = (f32x4){0.f, 0.f, 0.f, 0.f};
  gemm_mainloop64(X2 + (size_t)i0 * C_, W1b + (size_t)n0 * C_, 8, lds, acc,
                  (int)threadIdx.x);
  const int tid = threadIdx.x, lane = tid & 63, w = tid >> 6;
  const int wm = w >> 2, wn = w & 3, m16 = lane & 15, quad = lane >> 4;
  const int rbase = i0 + wm * 64, cbase = n0 + wn * 32;
#pragma unroll
  for (int m = 0; m < 4; ++m) {
#pragma unroll
    for (int g = 0; g < 4; ++g) {
      const int row = rbase + m * 16 + quad * 4 + g;
#pragma unroll
      for (int n = 0; n < 2; ++n) {
        const int col = cbase + n * 16 + m16;
        const float v = acc[m][n][g] + d1b[col];
        const float gl = 0.5f * v * (1.0f + erff(v * 0.70710678118654752f));
        H[(size_t)row * C_ + col] = f2bf(gl);
      }
    }
  }
}

// ---------------- MLP GEMM 2: out = X2 + H @ W2^T + b2 ----------------
__global__ __launch_bounds__(512, 4) void gemm_d2(
    const unsigned short* __restrict__ H, const unsigned short* __restrict__ W2b,
    const float* __restrict__ d2b, const unsigned short* __restrict__ X2,
    float* __restrict__ out) {
  __shared__ __align__(16) unsigned short lds[32768];
  const int swz = xcd_swizzle_1024((int)blockIdx.x);
  const int i0 = (swz & 255) * 128;
  const int n0 = (swz >> 8) * 128;
  f32x4 acc[4][2];
#pragma unroll
  for (int m = 0; m < 4; ++m)
#pragma unroll
    for (int n = 0; n < 2; ++n) acc[m][n] = (f32x4){0.f, 0.f, 0.f, 0.f};
  gemm_mainloop64(H + (size_t)i0 * C_, W2b + (size_t)n0 * C_, 8, lds, acc,
                  (int)threadIdx.x);
  const int tid = threadIdx.x, lane = tid & 63, w = tid >> 6;
  const int wm = w >> 2, wn = w & 3, m16 = lane & 15, quad = lane >> 4;
  const int rbase = i0 + wm * 64, cbase = n0 + wn * 32;
#pragma unroll
  for (int m = 0; m < 4; ++m) {
#pragma unroll
    for (int g = 0; g < 4; ++g) {
      const int row = rbase + m * 16 + quad * 4 + g;
#pragma unroll
      for (int n = 0; n < 2; ++n) {
        const int col = cbase + n * 16 + m16;
        out[(size_t)row * C_ + col] =
            acc[m][n][g] + d2b[col] + bf2f(X2[(size_t)row * C_ + col]);
      }
    }
  }
}

extern "C" void kernel_launch(void* const* d_in, const int* in_sizes, int n_in,
                              void* d_out, int out_size, void* d_ws, size_t ws_size,
                              hipStream_t stream) {
  const float* inp  = (const float*)d_in[0];
  const float* ln1w = (const float*)d_in[1];
  const float* ln1b = (const float*)d_in[2];
  const float* ln2w = (const float*)d_in[3];
  const float* ln2b = (const float*)d_in[4];
  const float* triM = (const float*)d_in[5];
  const float* trib = (const float*)d_in[6];
  const float* d1w  = (const float*)d_in[7];
  const float* d1b  = (const float*)d_in[8];
  const float* d2w  = (const float*)d_in[9];
  const float* d2b  = (const float*)d_in[10];
  float* out = (float*)d_out;

  char* ws = (char*)d_ws;
  float* red1p = (float*)ws;                        // 1024*2 floats (8 KB)
  float* red2  = (float*)(ws + 8192);               // 64*2 floats
  unsigned short* Mb  = (unsigned short*)(ws + 16384);
  unsigned short* W1b = Mb + TC_;
  unsigned short* W2b = W1b + TC_;
  unsigned short* XnT = W2b + TC_;                  // [B][C][T] bf16
  unsigned short* Z   = XnT + (size_t)B_ * TC_;     // [B][T][C] bf16
  unsigned short* X2  = Z + (size_t)B_ * TC_;       // [B][T][C] bf16
  unsigned short* H   = X2 + (size_t)B_ * TC_;      // [B*T][C] bf16

  prep<<<2048, 256, 0, stream>>>(triM, d1w, d2w, Mb, W1b, W2b, inp, red1p, red2);
  ln1_norm_t<<<dim3(8, 8, B_), 256, 0, stream>>>(inp, ln1w, ln1b, red1p, XnT);
  gemm_mixer<<<1024, 512, 0, stream>>>(Mb, XnT, trib, inp, Z, red2);
  ln2_norm<<<8192, 256, 0, stream>>>(Z, red2, ln2w, ln2b, X2);
  gemm_d1<<<1024, 512, 0, stream>>>(X2, W1b, d1b, H);
  gemm_d2<<<1024, 512, 0, stream>>>(H, W2b, d2b, X2, out);
}